// Round 10
// baseline (202.838 us; speedup 1.0000x reference)
//
#include <hip/hip_runtime.h>
#include <math.h>

typedef __attribute__((ext_vector_type(8))) short short8;
typedef __attribute__((ext_vector_type(8))) unsigned short ushort8;
typedef __attribute__((ext_vector_type(4))) float f32x4;

#define NTHR 256
#define LTHR 512
#define CAP 192  // bucket capacity; max in-degree of Poisson(64) over 10k nodes ~ 110

// ---------- bf16 helpers (RNE) ----------
__device__ __forceinline__ ushort f2bf(float f) {
    uint u = __float_as_uint(f);
    return (ushort)((u + 0x7FFFu + ((u >> 16) & 1u)) >> 16);
}
__device__ __forceinline__ uint pk2bf(float a, float b) {
    return (uint)f2bf(a) | ((uint)f2bf(b) << 16);
}
__device__ __forceinline__ float bfl(uint r) { return __uint_as_float(r << 16); }
__device__ __forceinline__ float bfh(uint r) { return __uint_as_float(r & 0xFFFF0000u); }

struct Params {
    const float* x; const float* dis;
    const float* W1; const float* b1;
    const float* W2; const float* b2;
    const float* W3; const float* b3;
    const float* Wout; const float* bout;
    const int* src; const int* dst; const int* ti;
    float* out;
    uint* degOut; uint* fill;          // adjacent: one memset zeroes both
    float* normOut; float* normIn;
    ushort* ebkt;                      // [N][CAP] src ids; tail padded to x8 with id N
    ushort* xbf;                       // [N+1][128], row N = zeros, rows pre-scaled by normOut
    ushort* w1t;                       // [256][128]  = W1^T
    ushort* w2t;                       // [256][256]  = W2^T
    ushort* w3t;                       // [64][256]   = W3^T
    ushort* bufB;                      // [N+1][256]
    ushort* bufC;                      // [N+1][64]
    float* av; float* bv;
    int N, E, P;
};

// ---------------- k_deg_scatter: one edge pass, 2 edges/thread ----------------
__global__ __launch_bounds__(NTHR) void k_deg_scatter(Params p) {
    int e = (blockIdx.x * NTHR + threadIdx.x) * 2;
    if (e + 1 < p.E) {
        int2 s2 = *(const int2*)&p.src[e];
        int2 d2 = *(const int2*)&p.dst[e];
        atomicAdd(&p.degOut[s2.x], 1u);
        atomicAdd(&p.degOut[s2.y], 1u);
        uint p0 = atomicAdd(&p.fill[d2.x], 1u);
        p.ebkt[(size_t)d2.x * CAP + p0] = (ushort)s2.x;
        uint p1 = atomicAdd(&p.fill[d2.y], 1u);
        p.ebkt[(size_t)d2.y * CAP + p1] = (ushort)s2.y;
    } else if (e < p.E) {
        int s = p.src[e];
        int v = p.dst[e];
        atomicAdd(&p.degOut[s], 1u);
        uint pos = atomicAdd(&p.fill[v], 1u);
        p.ebkt[(size_t)v * CAP + pos] = (ushort)s;
    }
}

// ------- k_norm_cvt: norms, bucket tail-pad, xbf (pre-scaled), W^T cvts, pad rows ------
__global__ __launch_bounds__(NTHR) void k_norm_cvt(Params p) {
    int gtid = blockIdx.x * NTHR + threadIdx.x;
    int GSZ = gridDim.x * NTHR;
    for (int v = gtid; v < p.N; v += GSZ) {
        uint d0 = p.degOut[v];
        uint d1 = p.fill[v];
        p.normOut[v] = d0 ? rsqrtf((float)d0) : 0.f;
        p.normIn[v] = d1 ? rsqrtf((float)d1) : 0.f;
        uint c8 = (d1 + 7) & ~7u;
        ushort* eb = p.ebkt + (size_t)v * CAP;
        for (uint j = d1; j < c8; ++j) eb[j] = (ushort)p.N;
    }
    // zero pad row N of xbf (64 uints), bufB (128), bufC (32)
    if (gtid < 64) ((uint*)&p.xbf[(size_t)p.N * 128])[gtid] = 0u;
    else if (gtid < 192) ((uint*)&p.bufB[(size_t)p.N * 256])[gtid - 64] = 0u;
    else if (gtid < 224) ((uint*)&p.bufC[(size_t)p.N * 64])[gtid - 192] = 0u;
    // xbf[v][c] = bf16(x[v][c] * normOut[v])
    int nx4 = p.N * 32;
    for (int i4 = gtid; i4 < nx4; i4 += GSZ) {
        int i = i4 * 4;
        int row = i >> 7;
        uint d0 = p.degOut[row];
        float no = d0 ? rsqrtf((float)d0) : 0.f;
        float4 v = *(const float4*)&p.x[i];
        uint2 pkv;
        pkv.x = pk2bf(v.x * no, v.y * no);
        pkv.y = pk2bf(v.z * no, v.w * no);
        *(uint2*)&p.xbf[i] = pkv;
    }
    // transposed weight conversions (read coalesced over source cols)
    for (int i = gtid; i < 128 * 256; i += GSZ) {
        int k = i >> 8, c = i & 255;
        p.w1t[c * 128 + k] = f2bf(p.W1[i]);
    }
    for (int i = gtid; i < 256 * 256; i += GSZ) {
        int k = i >> 8, c = i & 255;
        p.w2t[c * 256 + k] = f2bf(p.W2[i]);
    }
    for (int i = gtid; i < 256 * 64; i += GSZ) {
        int k = i >> 6, c = i & 63;
        p.w3t[c * 256 + k] = f2bf(p.W3[i]);
    }
}

// ---------------- k_layer1: fused agg1 (xbf -> LDS) + gemm1 -> bufB ----------------
// Block owns 32 nodes. 8 waves: agg 4 nodes each; then gemm rows 32 x cols 256, K=128.
__global__ __launch_bounds__(LTHR) void k_layer1(Params p) {
    __shared__ ushort As[32 * 136];  // [32][128+8]
    int m0 = blockIdx.x * 32;
    int wid = threadIdx.x >> 6;
    int l = threadIdx.x & 63;

    // ---- agg phase: wave wid handles rows wid*4 .. +3 ----
    const ushort* hb = p.xbf + l * 2;
#pragma unroll
    for (int i = 0; i < 4; ++i) {
        int r = wid * 4 + i;
        int v = m0 + r;
        uint pk = 0u;
        if (v < p.N) {
            int cnt = (int)p.fill[v];
            float nin = p.normIn[v];
            const ushort* eb = p.ebkt + (size_t)v * CAP;
            float a0 = 0.f, a1 = 0.f;
            int ngrp = (cnt + 7) >> 3;
            for (int g = 0; g < ngrp; ++g) {
                ushort8 w = *(const ushort8*)(eb + g * 8);
                uint gg[8];
#pragma unroll
                for (int j = 0; j < 8; ++j) gg[j] = *(const uint*)&hb[(int)w[j] * 128];
#pragma unroll
                for (int j = 0; j < 8; ++j) {
                    a0 += bfl(gg[j]);
                    a1 += bfh(gg[j]);
                }
            }
            pk = pk2bf(a0 * nin, a1 * nin);
        }
        *(uint*)&As[r * 136 + l * 2] = pk;
    }
    __syncthreads();

    // ---- gemm phase: wave wid: rowfrag rf = wid>>2, cols n0 = (wid&3)*64 ----
    int l15 = l & 15, l4 = l >> 4;
    int rf = wid >> 2;
    int n0 = (wid & 3) * 64;
    f32x4 acc[4] = {};
    const ushort* arow = &As[(rf * 16 + l15) * 136 + l4 * 8];
#pragma unroll
    for (int k0 = 0; k0 < 128; k0 += 32) {
        short8 af = *(const short8*)&arow[k0];
#pragma unroll
        for (int n = 0; n < 4; ++n) {
            short8 bf = *(const short8*)&p.w1t[(size_t)(n0 + n * 16 + l15) * 128 + k0 + l4 * 8];
            acc[n] = __builtin_amdgcn_mfma_f32_16x16x32_bf16(af, bf, acc[n], 0, 0, 0);
        }
    }
#pragma unroll
    for (int n = 0; n < 4; ++n) {
        int col = n0 + n * 16 + l15;
        float bs = p.b1[col];
#pragma unroll
        for (int q = 0; q < 4; ++q) {
            int row = m0 + rf * 16 + l4 * 4 + q;
            if (row < p.N) {
                float vv = fmaxf(acc[n][q] + bs, 0.f) * p.normOut[row];
                p.bufB[(size_t)row * 256 + col] = f2bf(vv);
            }
        }
    }
}

// ------- k_layer23: fused agg2 (bufB -> LDS) + gemm2 (->LDS) + gemm3 -> bufC -------
__global__ __launch_bounds__(LTHR) void k_layer23(Params p) {
    __shared__ ushort As[32 * 264];  // [32][256+8]
    __shared__ ushort Cs[32 * 264];
    int m0 = blockIdx.x * 32;
    int wid = threadIdx.x >> 6;
    int l = threadIdx.x & 63;
    int l15 = l & 15, l4 = l >> 4;

    // ---- agg2 phase: V=4 (uint2 per lane) ----
    const ushort* hb = p.bufB + l * 4;
#pragma unroll
    for (int i = 0; i < 4; ++i) {
        int r = wid * 4 + i;
        int v = m0 + r;
        uint2 pk = make_uint2(0u, 0u);
        if (v < p.N) {
            int cnt = (int)p.fill[v];
            float nin = p.normIn[v];
            const ushort* eb = p.ebkt + (size_t)v * CAP;
            float a0 = 0.f, a1 = 0.f, a2 = 0.f, a3 = 0.f;
            int ngrp = (cnt + 7) >> 3;
            for (int g = 0; g < ngrp; ++g) {
                ushort8 w = *(const ushort8*)(eb + g * 8);
                uint2 gg[8];
#pragma unroll
                for (int j = 0; j < 8; ++j) gg[j] = *(const uint2*)&hb[(int)w[j] * 256];
#pragma unroll
                for (int j = 0; j < 8; ++j) {
                    a0 += bfl(gg[j].x);
                    a1 += bfh(gg[j].x);
                    a2 += bfl(gg[j].y);
                    a3 += bfh(gg[j].y);
                }
            }
            pk.x = pk2bf(a0 * nin, a1 * nin);
            pk.y = pk2bf(a2 * nin, a3 * nin);
        }
        *(uint2*)&As[r * 264 + l * 4] = pk;
    }
    __syncthreads();

    // ---- gemm2 phase: rows 32 x cols 256, K=256; epilogue -> Cs = relu(.)+b2, *normOut ----
    {
        int rf = wid >> 2;
        int n0 = (wid & 3) * 64;
        f32x4 acc[4] = {};
        const ushort* arow = &As[(rf * 16 + l15) * 264 + l4 * 8];
#pragma unroll
        for (int k0 = 0; k0 < 256; k0 += 32) {
            short8 af = *(const short8*)&arow[k0];
#pragma unroll
            for (int n = 0; n < 4; ++n) {
                short8 bf = *(const short8*)&p.w2t[(size_t)(n0 + n * 16 + l15) * 256 + k0 + l4 * 8];
                acc[n] = __builtin_amdgcn_mfma_f32_16x16x32_bf16(af, bf, acc[n], 0, 0, 0);
            }
        }
#pragma unroll
        for (int n = 0; n < 4; ++n) {
            int col = n0 + n * 16 + l15;
            float bs = p.b2[col];
#pragma unroll
            for (int q = 0; q < 4; ++q) {
                int rl = rf * 16 + l4 * 4 + q;
                int row = m0 + rl;
                float no = (row < p.N) ? p.normOut[row] : 0.f;
                Cs[rl * 264 + col] = f2bf(fmaxf(acc[n][q] + bs, 0.f) * no);
            }
        }
    }
    __syncthreads();

    // ---- gemm3 phase: rows 32 x cols 64, K=256; one 16x16 tile per wave ----
    {
        int rf = wid & 1;
        int nf = wid >> 1;  // 0..3
        f32x4 acc = {};
        const ushort* arow = &Cs[(rf * 16 + l15) * 264 + l4 * 8];
#pragma unroll
        for (int k0 = 0; k0 < 256; k0 += 32) {
            short8 af = *(const short8*)&arow[k0];
            short8 bf = *(const short8*)&p.w3t[(size_t)(nf * 16 + l15) * 256 + k0 + l4 * 8];
            acc = __builtin_amdgcn_mfma_f32_16x16x32_bf16(af, bf, acc, 0, 0, 0);
        }
        int col = nf * 16 + l15;
#pragma unroll
        for (int q = 0; q < 4; ++q) {
            int row = m0 + rf * 16 + l4 * 4 + q;
            if (row < p.N) p.bufC[(size_t)row * 64 + col] = f2bf(acc[q]);
        }
    }
}

// ---------------- k_agg3: gather bufC + sigmoid + Wout dots -> av, bv ----------------
__global__ __launch_bounds__(NTHR) void k_agg3(Params p) {
    int v = blockIdx.x * 4 + (threadIdx.x >> 6);
    if (v >= p.N) return;
    int l = threadIdx.x & 63;
    const ushort* hb = p.bufC + l;
    const ushort* eb = p.ebkt + (size_t)v * CAP;
    int cnt = (int)p.fill[v];
    float nin = p.normIn[v];
    float acc = 0.f;
    int ngrp = (cnt + 7) >> 3;
    for (int g = 0; g < ngrp; ++g) {
        ushort8 w = *(const ushort8*)(eb + g * 8);
        ushort gg[8];
#pragma unroll
        for (int j = 0; j < 8; ++j) gg[j] = hb[(int)w[j] * 64];
#pragma unroll
        for (int j = 0; j < 8; ++j) acc += bfl((uint)gg[j]);
    }
    float g = acc * nin + p.b3[l];
    g = 1.f / (1.f + __expf(-g));
    float pa = g * p.Wout[l];
    float pb = g * p.Wout[64 + l];
#pragma unroll
    for (int off = 32; off > 0; off >>= 1) {
        pa += __shfl_down(pa, off);
        pb += __shfl_down(pb, off);
    }
    if (l == 0) {
        p.av[v] = pa;
        p.bv[v] = pb;
    }
}

// ---------------- final gather + tanh, 2 pairs/thread ----------------
__global__ __launch_bounds__(NTHR) void k_final(Params p) {
    int i = (blockIdx.x * NTHR + threadIdx.x) * 2;
    float w128 = p.Wout[128];
    float b0 = p.bout[0];
    if (i + 1 < p.P) {
        int2 o2 = *(const int2*)&p.ti[i];
        int2 d2 = *(const int2*)&p.ti[p.P + i];
        float dis0 = p.dis[(size_t)o2.x * p.N + d2.x];
        float dis1 = p.dis[(size_t)o2.y * p.N + d2.y];
        float s0 = p.av[o2.x] + p.bv[d2.x] + dis0 * w128 + b0;
        float s1 = p.av[o2.y] + p.bv[d2.y] + dis1 * w128 + b0;
        float2 r = make_float2(tanhf(s0), tanhf(s1));
        *(float2*)&p.out[i] = r;
    } else if (i < p.P) {
        int o = p.ti[i];
        int d = p.ti[p.P + i];
        float s = p.av[o] + p.bv[d] + p.dis[(size_t)o * p.N + d] * w128 + b0;
        p.out[i] = tanhf(s);
    }
}

extern "C" void kernel_launch(void* const* d_in, const int* in_sizes, int n_in,
                              void* d_out, int out_size, void* d_ws, size_t ws_size,
                              hipStream_t stream) {
    Params prm;
    prm.x    = (const float*)d_in[0];
    prm.dis  = (const float*)d_in[1];
    prm.W1   = (const float*)d_in[2];
    prm.b1   = (const float*)d_in[3];
    prm.W2   = (const float*)d_in[4];
    prm.b2   = (const float*)d_in[5];
    prm.W3   = (const float*)d_in[6];
    prm.b3   = (const float*)d_in[7];
    prm.Wout = (const float*)d_in[8];
    prm.bout = (const float*)d_in[9];
    prm.src  = (const int*)d_in[10];
    prm.dst  = (const int*)d_in[11];
    prm.ti   = (const int*)d_in[12];
    prm.out  = (float*)d_out;

    const int IN = 128, HID = 256, EMB = 64;
    prm.N = in_sizes[0] / IN;
    prm.E = in_sizes[10];
    prm.P = in_sizes[12] / 2;
    const int N = prm.N, E = prm.E, P = prm.P;

    char* ws = (char*)d_ws;
    size_t off = 0;
    auto alloc = [&](size_t bytes) {
        size_t o = off;
        off = (off + bytes + 255) & ~(size_t)255;
        return o;
    };
    size_t o_cnts = alloc((size_t)2 * N * 4);  // degOut | fill (adjacent, one memset)
    size_t o_nrmO = alloc((size_t)N * 4);
    size_t o_nrmI = alloc((size_t)N * 4);
    size_t o_ebkt = alloc((size_t)N * CAP * 2);
    size_t o_xbf  = alloc((size_t)(N + 1) * IN * 2);
    size_t o_w1   = alloc((size_t)IN * HID * 2);
    size_t o_w2   = alloc((size_t)HID * HID * 2);
    size_t o_w3   = alloc((size_t)HID * EMB * 2);
    size_t o_bufB = alloc((size_t)(N + 1) * HID * 2);
    size_t o_bufC = alloc((size_t)(N + 1) * EMB * 2);
    size_t o_av   = alloc((size_t)N * 4);
    size_t o_bv   = alloc((size_t)N * 4);
    (void)ws_size;

    prm.degOut  = (uint*)(ws + o_cnts);
    prm.fill    = prm.degOut + N;
    prm.normOut = (float*)(ws + o_nrmO);
    prm.normIn  = (float*)(ws + o_nrmI);
    prm.ebkt    = (ushort*)(ws + o_ebkt);
    prm.xbf     = (ushort*)(ws + o_xbf);
    prm.w1t     = (ushort*)(ws + o_w1);
    prm.w2t     = (ushort*)(ws + o_w2);
    prm.w3t     = (ushort*)(ws + o_w3);
    prm.bufB    = (ushort*)(ws + o_bufB);
    prm.bufC    = (ushort*)(ws + o_bufC);
    prm.av      = (float*)(ws + o_av);
    prm.bv      = (float*)(ws + o_bv);

    hipMemsetAsync(prm.degOut, 0, (size_t)2 * N * 4, stream);
    k_deg_scatter<<<(E / 2 + NTHR - 1) / NTHR, NTHR, 0, stream>>>(prm);
    k_norm_cvt<<<1024, NTHR, 0, stream>>>(prm);

    int nbl = (N + 31) / 32;  // 313 blocks
    k_layer1<<<nbl, LTHR, 0, stream>>>(prm);
    k_layer23<<<nbl, LTHR, 0, stream>>>(prm);
    k_agg3<<<(N + 3) / 4, NTHR, 0, stream>>>(prm);
    k_final<<<(P / 2 + NTHR - 1) / NTHR, NTHR, 0, stream>>>(prm);
}

// Round 11
// 180.929 us; speedup vs baseline: 1.1211x; 1.1211x over previous
//
#include <hip/hip_runtime.h>
#include <math.h>

typedef __attribute__((ext_vector_type(8))) short short8;
typedef __attribute__((ext_vector_type(8))) unsigned short ushort8;
typedef __attribute__((ext_vector_type(4))) float f32x4;

#define NTHR 256
#define CAP 192  // bucket capacity; max in-degree of Poisson(64) over 10k nodes ~ 110

// ---------- bf16 helpers (RNE) ----------
__device__ __forceinline__ ushort f2bf(float f) {
    uint u = __float_as_uint(f);
    return (ushort)((u + 0x7FFFu + ((u >> 16) & 1u)) >> 16);
}
__device__ __forceinline__ uint pk2bf(float a, float b) {
    return (uint)f2bf(a) | ((uint)f2bf(b) << 16);
}
__device__ __forceinline__ float bfl(uint r) { return __uint_as_float(r << 16); }
__device__ __forceinline__ float bfh(uint r) { return __uint_as_float(r & 0xFFFF0000u); }

struct Params {
    const float* x; const float* dis;
    const float* W1; const float* b1;
    const float* W2; const float* b2;
    const float* W3; const float* b3;
    const float* Wout; const float* bout;
    const int* src; const int* dst; const int* ti;
    float* out;
    uint* degOut; uint* fill;          // adjacent: one memset zeroes both
    float* normOut; float* normIn;
    ushort* ebkt;                      // [N][CAP] src ids; tail padded to x8 with id N
    ushort* xbf;                       // [N+1][128] pre-scaled by normOut; row N zeros
    ushort* w1t;                       // [256][128] = W1^T
    ushort* w2t;                       // [256][256] = W2^T
    ushort* w3t;                       // [64][256]  = W3^T
    ushort* bufA;                      // [N][256] scratch (agg outputs)
    ushort* bufB;                      // [N+1][256]
    ushort* bufC;                      // [N+1][64]
    float* av; float* bv;
    int N, E, P;
};

// ---------------- k_deg_scatter: one edge pass, 2 edges/thread ----------------
__global__ __launch_bounds__(NTHR) void k_deg_scatter(Params p) {
    int e = (blockIdx.x * NTHR + threadIdx.x) * 2;
    if (e + 1 < p.E) {
        int2 s2 = *(const int2*)&p.src[e];
        int2 d2 = *(const int2*)&p.dst[e];
        atomicAdd(&p.degOut[s2.x], 1u);
        atomicAdd(&p.degOut[s2.y], 1u);
        uint p0 = atomicAdd(&p.fill[d2.x], 1u);
        p.ebkt[(size_t)d2.x * CAP + p0] = (ushort)s2.x;
        uint p1 = atomicAdd(&p.fill[d2.y], 1u);
        p.ebkt[(size_t)d2.y * CAP + p1] = (ushort)s2.y;
    } else if (e < p.E) {
        int s = p.src[e];
        int v = p.dst[e];
        atomicAdd(&p.degOut[s], 1u);
        uint pos = atomicAdd(&p.fill[v], 1u);
        p.ebkt[(size_t)v * CAP + pos] = (ushort)s;
    }
}

// ------- k_norm_cvt: norms, bucket tail-pad, xbf (pre-scaled), W^T cvts, pad rows ------
__global__ __launch_bounds__(NTHR) void k_norm_cvt(Params p) {
    int gtid = blockIdx.x * NTHR + threadIdx.x;
    int GSZ = gridDim.x * NTHR;
    for (int v = gtid; v < p.N; v += GSZ) {
        uint d0 = p.degOut[v];
        uint d1 = p.fill[v];
        p.normOut[v] = d0 ? rsqrtf((float)d0) : 0.f;
        p.normIn[v] = d1 ? rsqrtf((float)d1) : 0.f;
        uint c8 = (d1 + 7) & ~7u;
        ushort* eb = p.ebkt + (size_t)v * CAP;
        for (uint j = d1; j < c8; ++j) eb[j] = (ushort)p.N;
    }
    // zero pad row N of xbf (64 uints), bufB (128), bufC (32)
    if (gtid < 64) ((uint*)&p.xbf[(size_t)p.N * 128])[gtid] = 0u;
    else if (gtid < 192) ((uint*)&p.bufB[(size_t)p.N * 256])[gtid - 64] = 0u;
    else if (gtid < 224) ((uint*)&p.bufC[(size_t)p.N * 64])[gtid - 192] = 0u;
    // xbf[v][c] = bf16(x[v][c] * normOut[v])
    int nx4 = p.N * 32;
    for (int i4 = gtid; i4 < nx4; i4 += GSZ) {
        int i = i4 * 4;
        int row = i >> 7;
        uint d0 = p.degOut[row];
        float no = d0 ? rsqrtf((float)d0) : 0.f;
        float4 v = *(const float4*)&p.x[i];
        uint2 pkv;
        pkv.x = pk2bf(v.x * no, v.y * no);
        pkv.y = pk2bf(v.z * no, v.w * no);
        *(uint2*)&p.xbf[i] = pkv;
    }
    // transposed weight conversions
    for (int i = gtid; i < 128 * 256; i += GSZ) {
        int k = i >> 8, c = i & 255;
        p.w1t[c * 128 + k] = f2bf(p.W1[i]);
    }
    for (int i = gtid; i < 256 * 256; i += GSZ) {
        int k = i >> 8, c = i & 255;
        p.w2t[c * 256 + k] = f2bf(p.W2[i]);
    }
    for (int i = gtid; i < 256 * 64; i += GSZ) {
        int k = i >> 6, c = i & 63;
        p.w3t[c * 256 + k] = f2bf(p.W3[i]);
    }
}

// ---------------- pure-sum bucket aggregation (R9-proven) ----------------
template <int V> struct GT;
template <> struct GT<1> { using T = ushort; };
template <> struct GT<2> { using T = uint; };

template <int V>
__device__ __forceinline__ void accum(float* acc, typename GT<V>::T g) {
    if constexpr (V == 1) {
        acc[0] += bfl((uint)g);
    } else {
        acc[0] += bfl(g);
        acc[1] += bfh(g);
    }
}

// SPLIT waves per node; wave `half` owns channels [half*64*V, (half+1)*64*V).
template <int D, int SPLIT, int ACT>
__global__ __launch_bounds__(NTHR) void k_agg(Params p, const ushort* __restrict__ h,
                                              ushort* __restrict__ outb) {
    constexpr int V = D / (64 * SPLIT);
    using T = typename GT<V>::T;
    int wib = threadIdx.x >> 6;
    int b = blockIdx.x;
    int v, half;
    if constexpr (SPLIT == 2) {
        half = b & 1;  // XCD parity: even/odd XCDs serve disjoint table halves
        v = (b >> 1) * 4 + wib;
    } else {
        half = 0;
        v = b * 4 + wib;
    }
    if (v >= p.N) return;
    int l = threadIdx.x & 63;
    const ushort* hb = h + half * (64 * V) + l * V;
    const ushort* eb = p.ebkt + (size_t)v * CAP;

    int cnt = (int)p.fill[v];
    float nin = p.normIn[v];
    float acc[V] = {};

    if (cnt > 0) {
        int ngrp = (cnt + 7) >> 3;
        ushort8 w = *(const ushort8*)eb;
        T gp[8];
#pragma unroll
        for (int j = 0; j < 8; ++j) gp[j] = *(const T*)&hb[(int)w[j] * D];
        for (int g = 1; g < ngrp; ++g) {
            ushort8 wn = *(const ushort8*)(eb + g * 8);
            T gn[8];
#pragma unroll
            for (int j = 0; j < 8; ++j) gn[j] = *(const T*)&hb[(int)wn[j] * D];
#pragma unroll
            for (int j = 0; j < 8; ++j) accum<V>(acc, gp[j]);
#pragma unroll
            for (int j = 0; j < 8; ++j) gp[j] = gn[j];
        }
#pragma unroll
        for (int j = 0; j < 8; ++j) accum<V>(acc, gp[j]);
    }

    if constexpr (ACT == 0) {
        if constexpr (V == 2) {
            *(uint*)&outb[(size_t)v * D + half * (64 * V) + l * V] =
                pk2bf(acc[0] * nin, acc[1] * nin);
        } else {
            outb[(size_t)v * D + half * 64 + l] = f2bf(acc[0] * nin);
        }
    } else {
        float g = acc[0] * nin + p.b3[l];
        g = 1.f / (1.f + __expf(-g));
        float pa = g * p.Wout[l];
        float pb = g * p.Wout[64 + l];
#pragma unroll
        for (int off = 32; off > 0; off >>= 1) {
            pa += __shfl_down(pa, off);
            pb += __shfl_down(pb, off);
        }
        if (l == 0) {
            p.av[v] = pa;
            p.bv[v] = pb;
        }
    }
}

// ------- k_gemm1: LDS-free barrier-free. bufA[N,128] @ W1 (+b1, relu, *normOut) -> bufB -------
// grid (ceil(N/64), 4); 4 waves/block, wave w: rows m0+w*16..+15, cols n0..n0+63.
__global__ __launch_bounds__(NTHR) void k_gemm1(Params p) {
    int wid = threadIdx.x >> 6;
    int l = threadIdx.x & 63;
    int l15 = l & 15, l4 = l >> 4;
    int m0 = blockIdx.x * 64;
    int n0 = blockIdx.y * 64;
    int row = m0 + wid * 16 + l15;
    bool rok = row < p.N;
    const ushort* Ab = p.bufA + (size_t)row * 128 + l4 * 8;

    f32x4 acc[4] = {};
#pragma unroll
    for (int k0 = 0; k0 < 128; k0 += 32) {
        short8 af = {};
        if (rok) af = *(const short8*)&Ab[k0];
#pragma unroll
        for (int n = 0; n < 4; ++n) {
            short8 bf = *(const short8*)&p.w1t[(size_t)(n0 + n * 16 + l15) * 128 + k0 + l4 * 8];
            acc[n] = __builtin_amdgcn_mfma_f32_16x16x32_bf16(af, bf, acc[n], 0, 0, 0);
        }
    }
#pragma unroll
    for (int n = 0; n < 4; ++n) {
        int col = n0 + n * 16 + l15;
        float bs = p.b1[col];
#pragma unroll
        for (int q = 0; q < 4; ++q) {
            int grow = m0 + wid * 16 + l4 * 4 + q;
            if (grow < p.N) {
                float vv = fmaxf(acc[n][q] + bs, 0.f) * p.normOut[grow];
                p.bufB[(size_t)grow * 256 + col] = f2bf(vv);
            }
        }
    }
}

// ------- k_gemm23: fused gemm2 (+b2, relu, *normOut -> LDS) + gemm3 -> bufC -------
// BM=32, 256 thr (4 waves). gemm2: wave w: rowfrag w&1, coltiles (w>>1)*8..+7 (K=256).
// gemm3 from LDS: wave w: rowfrag w&1, coltiles (w>>1)*2..+1 (K=256).
__global__ __launch_bounds__(NTHR) void k_gemm23(Params p) {
    __shared__ ushort Cs[32 * 264];
    int wid = threadIdx.x >> 6;
    int l = threadIdx.x & 63;
    int l15 = l & 15, l4 = l >> 4;
    int m0 = blockIdx.x * 32;
    int rfrag = wid & 1;
    int chunk = wid >> 1;  // 0..1

    // ---- gemm2 ----
    {
        int row = m0 + rfrag * 16 + l15;
        bool rok = row < p.N;
        const ushort* Ab = p.bufA + (size_t)row * 256 + l4 * 8;
        f32x4 acc[8] = {};
#pragma unroll
        for (int k0 = 0; k0 < 256; k0 += 32) {
            short8 af = {};
            if (rok) af = *(const short8*)&Ab[k0];
#pragma unroll
            for (int n = 0; n < 8; ++n) {
                int col = chunk * 128 + n * 16 + l15;
                short8 bf = *(const short8*)&p.w2t[(size_t)col * 256 + k0 + l4 * 8];
                acc[n] = __builtin_amdgcn_mfma_f32_16x16x32_bf16(af, bf, acc[n], 0, 0, 0);
            }
        }
#pragma unroll
        for (int n = 0; n < 8; ++n) {
            int col = chunk * 128 + n * 16 + l15;
            float bs = p.b2[col];
#pragma unroll
            for (int q = 0; q < 4; ++q) {
                int rl = rfrag * 16 + l4 * 4 + q;
                int grow = m0 + rl;
                float no = (grow < p.N) ? p.normOut[grow] : 0.f;
                Cs[rl * 264 + col] = f2bf(fmaxf(acc[n][q] + bs, 0.f) * no);
            }
        }
    }
    __syncthreads();

    // ---- gemm3 ----
    {
        const ushort* arow = &Cs[(rfrag * 16 + l15) * 264 + l4 * 8];
        f32x4 a3[2] = {};
#pragma unroll
        for (int k0 = 0; k0 < 256; k0 += 32) {
            short8 af = *(const short8*)&arow[k0];
#pragma unroll
            for (int n = 0; n < 2; ++n) {
                int col = chunk * 32 + n * 16 + l15;
                short8 bf = *(const short8*)&p.w3t[(size_t)col * 256 + k0 + l4 * 8];
                a3[n] = __builtin_amdgcn_mfma_f32_16x16x32_bf16(af, bf, a3[n], 0, 0, 0);
            }
        }
#pragma unroll
        for (int n = 0; n < 2; ++n) {
            int col = chunk * 32 + n * 16 + l15;
#pragma unroll
            for (int q = 0; q < 4; ++q) {
                int grow = m0 + rfrag * 16 + l4 * 4 + q;
                if (grow < p.N) p.bufC[(size_t)grow * 64 + col] = f2bf(a3[n][q]);
            }
        }
    }
}

// ---------------- final gather + tanh, 2 pairs/thread ----------------
__global__ __launch_bounds__(NTHR) void k_final(Params p) {
    int i = (blockIdx.x * NTHR + threadIdx.x) * 2;
    float w128 = p.Wout[128];
    float b0 = p.bout[0];
    if (i + 1 < p.P) {
        int2 o2 = *(const int2*)&p.ti[i];
        int2 d2 = *(const int2*)&p.ti[p.P + i];
        float dis0 = p.dis[(size_t)o2.x * p.N + d2.x];
        float dis1 = p.dis[(size_t)o2.y * p.N + d2.y];
        float s0 = p.av[o2.x] + p.bv[d2.x] + dis0 * w128 + b0;
        float s1 = p.av[o2.y] + p.bv[d2.y] + dis1 * w128 + b0;
        float2 r = make_float2(tanhf(s0), tanhf(s1));
        *(float2*)&p.out[i] = r;
    } else if (i < p.P) {
        int o = p.ti[i];
        int d = p.ti[p.P + i];
        float s = p.av[o] + p.bv[d] + p.dis[(size_t)o * p.N + d] * w128 + b0;
        p.out[i] = tanhf(s);
    }
}

extern "C" void kernel_launch(void* const* d_in, const int* in_sizes, int n_in,
                              void* d_out, int out_size, void* d_ws, size_t ws_size,
                              hipStream_t stream) {
    Params prm;
    prm.x    = (const float*)d_in[0];
    prm.dis  = (const float*)d_in[1];
    prm.W1   = (const float*)d_in[2];
    prm.b1   = (const float*)d_in[3];
    prm.W2   = (const float*)d_in[4];
    prm.b2   = (const float*)d_in[5];
    prm.W3   = (const float*)d_in[6];
    prm.b3   = (const float*)d_in[7];
    prm.Wout = (const float*)d_in[8];
    prm.bout = (const float*)d_in[9];
    prm.src  = (const int*)d_in[10];
    prm.dst  = (const int*)d_in[11];
    prm.ti   = (const int*)d_in[12];
    prm.out  = (float*)d_out;

    const int IN = 128, HID = 256, EMB = 64;
    prm.N = in_sizes[0] / IN;
    prm.E = in_sizes[10];
    prm.P = in_sizes[12] / 2;
    const int N = prm.N, E = prm.E, P = prm.P;

    char* ws = (char*)d_ws;
    size_t off = 0;
    auto alloc = [&](size_t bytes) {
        size_t o = off;
        off = (off + bytes + 255) & ~(size_t)255;
        return o;
    };
    size_t o_cnts = alloc((size_t)2 * N * 4);  // degOut | fill
    size_t o_nrmO = alloc((size_t)N * 4);
    size_t o_nrmI = alloc((size_t)N * 4);
    size_t o_ebkt = alloc((size_t)N * CAP * 2);
    size_t o_xbf  = alloc((size_t)(N + 1) * IN * 2);
    size_t o_w1   = alloc((size_t)IN * HID * 2);
    size_t o_w2   = alloc((size_t)HID * HID * 2);
    size_t o_w3   = alloc((size_t)HID * EMB * 2);
    size_t o_bufA = alloc((size_t)N * HID * 2);
    size_t o_bufB = alloc((size_t)(N + 1) * HID * 2);
    size_t o_bufC = alloc((size_t)(N + 1) * EMB * 2);
    size_t o_av   = alloc((size_t)N * 4);
    size_t o_bv   = alloc((size_t)N * 4);
    (void)ws_size;

    prm.degOut  = (uint*)(ws + o_cnts);
    prm.fill    = prm.degOut + N;
    prm.normOut = (float*)(ws + o_nrmO);
    prm.normIn  = (float*)(ws + o_nrmI);
    prm.ebkt    = (ushort*)(ws + o_ebkt);
    prm.xbf     = (ushort*)(ws + o_xbf);
    prm.w1t     = (ushort*)(ws + o_w1);
    prm.w2t     = (ushort*)(ws + o_w2);
    prm.w3t     = (ushort*)(ws + o_w3);
    prm.bufA    = (ushort*)(ws + o_bufA);
    prm.bufB    = (ushort*)(ws + o_bufB);
    prm.bufC    = (ushort*)(ws + o_bufC);
    prm.av      = (float*)(ws + o_av);
    prm.bv      = (float*)(ws + o_bv);

    hipMemsetAsync(prm.degOut, 0, (size_t)2 * N * 4, stream);
    k_deg_scatter<<<(E / 2 + NTHR - 1) / NTHR, NTHR, 0, stream>>>(prm);
    k_norm_cvt<<<1024, NTHR, 0, stream>>>(prm);

    int nb4 = (N + 3) / 4;

    // layer1: agg1 -> bufA[N,128] ; gemm1 -> bufB[N,256]
    k_agg<128, 1, 0><<<nb4, NTHR, 0, stream>>>(prm, prm.xbf, prm.bufA);
    {
        dim3 grid((N + 63) / 64, 4);
        k_gemm1<<<grid, NTHR, 0, stream>>>(prm);
    }
    // layer2+3: agg2 -> bufA[N,256] ; fused gemm2+gemm3 -> bufC[N,64]
    k_agg<256, 2, 0><<<nb4 * 2, NTHR, 0, stream>>>(prm, prm.bufB, prm.bufA);
    k_gemm23<<<(N + 31) / 32, NTHR, 0, stream>>>(prm);
    // layer3 agg + sigmoid + Wout dots
    k_agg<64, 1, 2><<<nb4, NTHR, 0, stream>>>(prm, prm.bufC, nullptr);
    k_final<<<(P / 2 + NTHR - 1) / NTHR, NTHR, 0, stream>>>(prm);
}